// Round 2
// baseline (882.777 us; speedup 1.0000x reference)
//
#include <hip/hip_runtime.h>
#include <hip/hip_fp16.h>

#define NN 100000
#define NE 3200000
#define FIN 300
#define HID 16
#define NC 10
#define PADCAP 3500064      // >= sum of pad4(cnt_i) <= NE + 3*NN = 3,500,000
#define NBLK 98             // ceil(NN / 1024)

__device__ __forceinline__ int pad4(int x) { return (x + 3) & ~3; }

// ---- init ------------------------------------------------------------------

__global__ void k_init_deg(float* __restrict__ deg) {
    int i = blockIdx.x * blockDim.x + threadIdx.x;
    if (i < NN) deg[i] = 1.0f;   // self-loop weight
}

// count in-degree (int) and weighted degree (float) in one pass
__global__ void k_cnt(const int* __restrict__ col, const float* __restrict__ w,
                      int* __restrict__ cnt, float* __restrict__ deg) {
    int e = blockIdx.x * blockDim.x + threadIdx.x;
    if (e < NE) {
        int c = col[e];
        atomicAdd(&cnt[c], 1);
        atomicAdd(&deg[c], w[e]);
    }
}

__global__ void k_dinv(float* __restrict__ deg) {
    int i = blockIdx.x * blockDim.x + threadIdx.x;
    if (i < NN) deg[i] = rsqrtf(deg[i]);   // deg >= 1 always
}

// ---- exclusive scan of pad4(cnt), 3 phases ---------------------------------

__global__ void k_scanA(const int* __restrict__ cnt, int* __restrict__ bsum) {
    __shared__ int lds[256];
    int b = blockIdx.x, t = threadIdx.x;
    int base = b * 1024 + t * 4;
    int s = 0;
    #pragma unroll
    for (int q = 0; q < 4; ++q) { int i = base + q; if (i < NN) s += pad4(cnt[i]); }
    lds[t] = s; __syncthreads();
    for (int off = 128; off > 0; off >>= 1) {
        if (t < off) lds[t] += lds[t + off];
        __syncthreads();
    }
    if (t == 0) bsum[b] = lds[0];
}

__global__ void k_scanB(int* __restrict__ bsum) {
    __shared__ int lds[128];
    int t = threadIdx.x;
    int v = (t < NBLK) ? bsum[t] : 0;
    lds[t] = v; __syncthreads();
    for (int off = 1; off < 128; off <<= 1) {
        int add = (t >= off) ? lds[t - off] : 0;
        __syncthreads();
        lds[t] += add;
        __syncthreads();
    }
    if (t < NBLK) bsum[t] = lds[t] - v;   // exclusive
}

// in-place: cnt -> padded segment starts; also writes cursor copy and total at ip[NN]
__global__ void k_scanC(int* __restrict__ ip, int* __restrict__ cursor,
                        const int* __restrict__ bofs) {
    __shared__ int lds[256];
    int b = blockIdx.x, t = threadIdx.x;
    int base = b * 1024 + t * 4;
    int v[4]; int s = 0;
    #pragma unroll
    for (int q = 0; q < 4; ++q) { int i = base + q; v[q] = (i < NN) ? pad4(ip[i]) : 0; s += v[q]; }
    lds[t] = s; __syncthreads();
    int own = s;
    for (int off = 1; off < 256; off <<= 1) {
        int add = (t >= off) ? lds[t - off] : 0;
        __syncthreads();
        lds[t] += add;
        __syncthreads();
    }
    int run = bofs[b] + lds[t] - own;
    #pragma unroll
    for (int q = 0; q < 4; ++q) {
        int i = base + q;
        if (i < NN) {
            ip[i] = run; cursor[i] = run;
            if (i == NN - 1) ip[NN] = run + v[q];
            run += v[q];
        }
    }
}

// ---- fill CSC: srow (source node), a = dinv[row]*w (fp16) ------------------

__global__ void k_fill(const int* __restrict__ row, const int* __restrict__ col,
                       const float* __restrict__ w, const float* __restrict__ dinv,
                       int* __restrict__ cursor, int* __restrict__ srow,
                       __half* __restrict__ a) {
    int e = blockIdx.x * blockDim.x + threadIdx.x;
    if (e >= NE) return;
    int r = row[e], c = col[e];
    int p = atomicAdd(&cursor[c], 1);
    srow[p] = r;
    a[p] = __float2half(dinv[r] * w[e]);
}

// ---- x @ W1 : [NN,300] x [300,16] ------------------------------------------

__global__ void k_xw(const float* __restrict__ x, const float* __restrict__ W1,
                     float* __restrict__ xw) {
    __shared__ float w1s[FIN * HID];
    for (int i = threadIdx.x; i < FIN * HID; i += blockDim.x) w1s[i] = W1[i];
    __syncthreads();
    long t = (long)blockIdx.x * blockDim.x + threadIdx.x;
    int node = (int)(t >> 4), c = (int)(t & 15);
    if (node >= NN) return;
    const float4* xr = (const float4*)(x + (long)node * FIN);  // 300 = 75 * 4
    float acc = 0.f;
    #pragma unroll 5
    for (int q = 0; q < FIN / 4; ++q) {
        float4 f = xr[q];
        int k = 4 * q;
        acc = fmaf(f.x, w1s[(k + 0) * HID + c], acc);
        acc = fmaf(f.y, w1s[(k + 1) * HID + c], acc);
        acc = fmaf(f.z, w1s[(k + 2) * HID + c], acc);
        acc = fmaf(f.w, w1s[(k + 3) * HID + c], acc);
    }
    xw[node * HID + c] = acc;
}

// ---- layer 1 pull-gather, fused +b1, relu, @W2 -> hw2 ----------------------
// 16 lanes per node; c = feature. Padded entries have a=0 -> contribute 0.

__global__ void k_gather1(const int* __restrict__ ip, const int* __restrict__ srow,
                          const __half* __restrict__ a, const float* __restrict__ xw,
                          const float* __restrict__ dinv, const float* __restrict__ b1,
                          const float* __restrict__ W2, float* __restrict__ hw2) {
    __shared__ float w2s[HID * NC];
    if (threadIdx.x < HID * NC) w2s[threadIdx.x] = W2[threadIdx.x];
    __syncthreads();
    long t = (long)blockIdx.x * blockDim.x + threadIdx.x;
    int i = (int)(t >> 4), c = (int)(t & 15);
    int s = ip[i], epad = ip[i + 1];
    float acc = 0.f;
    for (int k = s; k < epad; k += 4) {
        int4 r4 = *(const int4*)(srow + k);
        float2 f01 = __half22float2(*(const __half2*)(a + k));
        float2 f23 = __half22float2(*(const __half2*)(a + k + 2));
        acc = fmaf(f01.x, xw[(long)r4.x * HID + c], acc);
        acc = fmaf(f01.y, xw[(long)r4.y * HID + c], acc);
        acc = fmaf(f23.x, xw[(long)r4.z * HID + c], acc);
        acc = fmaf(f23.y, xw[(long)r4.w * HID + c], acc);
    }
    float di = dinv[i];
    float h = fmaf(di, acc, di * di * xw[(long)i * HID + c]) + b1[c];
    h = fmaxf(h, 0.f);
    // h @ W2 across the 16-lane group
    int jj = (c < NC) ? c : 0;
    float acc2 = 0.f;
    #pragma unroll
    for (int k2 = 0; k2 < HID; ++k2) {
        float hk = __shfl(h, k2, HID);
        acc2 = fmaf(hk, w2s[k2 * NC + jj], acc2);
    }
    if (c < NC) hw2[(long)i * NC + c] = acc2;
}

// ---- layer 2 pull-gather, fused +b2, log_softmax -> out --------------------

__global__ void k_gather2(const int* __restrict__ ip, const int* __restrict__ srow,
                          const __half* __restrict__ a, const float* __restrict__ hw2,
                          const float* __restrict__ dinv, const float* __restrict__ b2,
                          float* __restrict__ out) {
    long t = (long)blockIdx.x * blockDim.x + threadIdx.x;
    int i = (int)(t >> 4), j = (int)(t & 15);
    int s = ip[i], epad = ip[i + 1];
    float acc = 0.f;
    if (j < NC) {
        for (int k = s; k < epad; k += 4) {
            int4 r4 = *(const int4*)(srow + k);
            float2 f01 = __half22float2(*(const __half2*)(a + k));
            float2 f23 = __half22float2(*(const __half2*)(a + k + 2));
            acc = fmaf(f01.x, hw2[(long)r4.x * NC + j], acc);
            acc = fmaf(f01.y, hw2[(long)r4.y * NC + j], acc);
            acc = fmaf(f23.x, hw2[(long)r4.z * NC + j], acc);
            acc = fmaf(f23.y, hw2[(long)r4.w * NC + j], acc);
        }
    }
    float di = dinv[i];
    float v = (j < NC) ? fmaf(di, acc, di * di * hw2[(long)i * NC + j]) + b2[j] : -1e30f;
    float m = v;
    #pragma unroll
    for (int mask = 8; mask > 0; mask >>= 1) m = fmaxf(m, __shfl_xor(m, mask, HID));
    float ev = (j < NC) ? __expf(v - m) : 0.f;
    float ssum = ev;
    #pragma unroll
    for (int mask = 8; mask > 0; mask >>= 1) ssum += __shfl_xor(ssum, mask, HID);
    if (j < NC) out[(long)i * NC + j] = v - m - __logf(ssum);
}

// ---- launch -----------------------------------------------------------------

extern "C" void kernel_launch(void* const* d_in, const int* in_sizes, int n_in,
                              void* d_out, int out_size, void* d_ws, size_t ws_size,
                              hipStream_t stream) {
    const float* x  = (const float*)d_in[0];
    const int*   ei = (const int*)d_in[1];     // [2, E] row-major (int32 from harness)
    const float* ew = (const float*)d_in[2];
    const float* W1 = (const float*)d_in[3];
    const float* b1 = (const float*)d_in[4];
    const float* W2 = (const float*)d_in[5];
    const float* b2 = (const float*)d_in[6];
    float* out = (float*)d_out;

    const int* row = ei;
    const int* col = ei + NE;

    // workspace layout (words)
    int*    ip     = (int*)d_ws;               // NN+1 (doubles as cnt pre-scan)
    int*    cursor = ip + NN + 1;              // NN
    float*  deg    = (float*)(cursor + NN);    // NN (becomes dinv)
    int*    bsum   = (int*)(deg + NN);         // 128
    size_t  o      = (size_t)(NN + 1) + NN + NN + 128;
    o = (o + 3) & ~(size_t)3;                  // 16B-align srow for int4 loads
    int*    srow   = (int*)d_ws + o;           // PADCAP ints
    __half* a      = (__half*)(srow + PADCAP); // PADCAP halves
    float*  xw     = (float*)(a + PADCAP);     // NN*HID
    float*  hw2    = xw + (size_t)NN * HID;    // NN*NC

    hipMemsetAsync(ip, 0, (NN + 1) * sizeof(int), stream);
    hipMemsetAsync(srow, 0, (size_t)PADCAP * 6, stream);  // srow + a contiguous

    k_init_deg<<<(NN + 255) / 256, 256, 0, stream>>>(deg);
    k_cnt<<<(NE + 255) / 256, 256, 0, stream>>>(col, ew, ip, deg);
    k_dinv<<<(NN + 255) / 256, 256, 0, stream>>>(deg);

    k_scanA<<<NBLK, 256, 0, stream>>>(ip, bsum);
    k_scanB<<<1, 128, 0, stream>>>(bsum);
    k_scanC<<<NBLK, 256, 0, stream>>>(ip, cursor, bsum);

    k_fill<<<(NE + 255) / 256, 256, 0, stream>>>(row, col, ew, deg, cursor, srow, a);

    k_xw<<<(int)(((long)NN * 16 + 255) / 256), 256, 0, stream>>>(x, W1, xw);
    k_gather1<<<(int)(((long)NN * 16) / 256), 256, 0, stream>>>(ip, srow, a, xw, deg, b1, W2, hw2);
    k_gather2<<<(int)(((long)NN * 16) / 256), 256, 0, stream>>>(ip, srow, a, hw2, deg, b2, out);
}